// Round 15
// baseline (303.812 us; speedup 1.0000x reference)
//
#include <hip/hip_runtime.h>
#include <hip/hip_bf16.h>

typedef __attribute__((ext_vector_type(8))) short bv8;
typedef __attribute__((ext_vector_type(4))) float fv4;
typedef __hip_bfloat16 bf16;

#define MFMA16(a,b,c) __builtin_amdgcn_mfma_f32_16x16x32_bf16((a),(b),(c),0,0,0)
#define GLOAD_LDS(gp, lp) __builtin_amdgcn_global_load_lds( \
    (const __attribute__((address_space(1))) void*)(gp), \
    (__attribute__((address_space(3))) void*)(lp), 16, 0, 0)

// ---------------- block reduce helpers ----------------
template<int NW>
__device__ __forceinline__ float blockReduceSumF(float v) {
  #pragma unroll
  for (int m = 1; m < 64; m <<= 1) v += __shfl_xor(v, m, 64);
  __shared__ float sm[NW];
  if ((threadIdx.x & 63) == 0) sm[threadIdx.x >> 6] = v;
  __syncthreads();
  float t = 0.f;
  #pragma unroll
  for (int i = 0; i < NW; ++i) t += sm[i];
  __syncthreads();
  return t;
}

template<int NW>
__device__ __forceinline__ double blockReduceMaxD(double v) {
  #pragma unroll
  for (int m = 1; m < 64; m <<= 1) v = fmax(v, __shfl_xor(v, m, 64));
  __shared__ double sm[NW];
  if ((threadIdx.x & 63) == 0) sm[threadIdx.x >> 6] = v;
  __syncthreads();
  double t = sm[0];
  #pragma unroll
  for (int i = 1; i < NW; ++i) t = fmax(t, sm[i]);
  __syncthreads();
  return t;
}

// ---------------- prep: fused LN+sdot (16384) | weight cast (2048) | posq init (16) ----------------
__global__ __launch_bounds__(256)
void prep_kernel(const float* __restrict__ x, const float* __restrict__ lnw,
                 const float* __restrict__ lnb, const float* __restrict__ rtq,
                 const float* __restrict__ rtkv, bf16* __restrict__ lnout,
                 double* __restrict__ s,
                 const float* __restrict__ a0, const float* __restrict__ a1,
                 const float* __restrict__ a2, const float* __restrict__ a3,
                 const float* __restrict__ a4,
                 bf16* __restrict__ b0, bf16* __restrict__ b1, bf16* __restrict__ b2,
                 bf16* __restrict__ b3, bf16* __restrict__ b4,
                 int* __restrict__ posq) {
  const int bid = blockIdx.x;
  if (bid < 16384) {
    const int r = bid;
    const float* xr = x + (size_t)r * 1024;
    float v4[4]; float ssum = 0.f;
    double dq = 0.0, dk = 0.0;
    #pragma unroll
    for (int i = 0; i < 4; ++i) {
      int d = threadIdx.x + i * 256;
      float v = xr[d];
      v4[i] = v; ssum += v;
      dq += (double)v * (double)rtq[d];
      dk += (double)v * (double)rtkv[d];
    }
    ssum = blockReduceSumF<4>(ssum);
    const float mean = ssum * (1.0f / 1024.0f);
    float vs = 0.f;
    #pragma unroll
    for (int i = 0; i < 4; ++i) { float d = v4[i] - mean; vs += d * d; }
    vs = blockReduceSumF<4>(vs);
    const float rstd = 1.0f / sqrtf(vs * (1.0f / 1024.0f) + 1e-5f);
    #pragma unroll
    for (int m = 1; m < 64; m <<= 1) { dq += __shfl_xor(dq, m, 64); dk += __shfl_xor(dk, m, 64); }
    __shared__ double smq[4], smk[4];
    if ((threadIdx.x & 63) == 0) { smq[threadIdx.x >> 6] = dq; smk[threadIdx.x >> 6] = dk; }
    __syncthreads();
    if (threadIdx.x == 0) {
      s[r] = smq[0] + smq[1] + smq[2] + smq[3];
      s[16384 + r] = smk[0] + smk[1] + smk[2] + smk[3];
    }
    bf16* orow = lnout + (size_t)r * 1024;
    #pragma unroll
    for (int i = 0; i < 4; ++i) {
      int d = threadIdx.x + i * 256;
      orow[d] = __float2bfloat16((v4[i] - mean) * rstd * lnw[d] + lnb[d]);
    }
  } else if (bid < 18432) {
    size_t g = ((size_t)(bid - 16384) * 256 + threadIdx.x) * 8;
    const float* src; bf16* dst; size_t off;
    if (g < 1572864)      { src = a0; dst = b0; off = g; }
    else if (g < 2097152) { src = a1; dst = b1; off = g - 1572864; }
    else if (g < 2621440) { src = a2; dst = b2; off = g - 2097152; }
    else if (g < 3670016) { src = a3; dst = b3; off = g - 2621440; }
    else                  { src = a4; dst = b4; off = g - 3670016; }
    float4 v0 = *(const float4*)(src + off);
    float4 v1 = *(const float4*)(src + off + 4);
    bv8 o;
    ((bf16*)&o)[0] = __float2bfloat16(v0.x); ((bf16*)&o)[1] = __float2bfloat16(v0.y);
    ((bf16*)&o)[2] = __float2bfloat16(v0.z); ((bf16*)&o)[3] = __float2bfloat16(v0.w);
    ((bf16*)&o)[4] = __float2bfloat16(v1.x); ((bf16*)&o)[5] = __float2bfloat16(v1.y);
    ((bf16*)&o)[6] = __float2bfloat16(v1.z); ((bf16*)&o)[7] = __float2bfloat16(v1.w);
    *(bv8*)(dst + off) = o;
  } else {
    int i0 = (bid - 18432) * 1024 + threadIdx.x * 4;
    posq[i0] = -1; posq[i0 + 1] = -1; posq[i0 + 2] = -1; posq[i0 + 3] = -1;
  }
}

// ---------------- GEMM 128x128 core, BK=64 with st-XOR swizzle ----------------
// EPI: 0 = bf16 store, 1 = f32 store, 2 = f32 store + combine (light + heavy/null_q)
template<int EPI>
__device__ __forceinline__ void gemm_core(
    const bf16* __restrict__ A, const bf16* __restrict__ B, void* __restrict__ Cout,
    int N, int K, int row0, int col0, bf16* As, bf16* Bs,
    const int* __restrict__ posq, const float* __restrict__ heavy,
    const float* __restrict__ nullq) {
  const int tid = threadIdx.x;
  const int lane = tid & 63, w = tid >> 6;
  const int wr = w >> 1, wc = w & 1;
  const int lrow = lane & 15, lkg = lane >> 4;
  fv4 acc[4][4];
  #pragma unroll
  for (int m = 0; m < 4; ++m)
    #pragma unroll
    for (int n = 0; n < 4; ++n) acc[m][n] = (fv4){0.f, 0.f, 0.f, 0.f};
  const int ob0 = w * 1024;
  for (int k0 = 0; k0 < K; k0 += 64) {
    #pragma unroll
    for (int t = 0; t < 4; ++t) {
      int ob = t * 4096 + ob0;
      int byteL = ob + lane * 16;
      int r = byteL >> 7;
      int cU = ((byteL >> 4) & 7) ^ (r & 7);
      GLOAD_LDS(A + (size_t)(row0 + r) * K + k0 + cU * 8, (char*)As + ob);
      GLOAD_LDS(B + (size_t)(col0 + r) * K + k0 + cU * 8, (char*)Bs + ob);
    }
    __syncthreads();
    #pragma unroll
    for (int ks = 0; ks < 2; ++ks) {
      bv8 af[4], bfr[4];
      #pragma unroll
      for (int m = 0; m < 4; ++m) {
        int row = wr * 64 + m * 16 + lrow;
        af[m] = *(bv8*)((char*)As + row * 128 + (((ks * 4 + lkg) ^ (row & 7)) << 4));
      }
      #pragma unroll
      for (int n = 0; n < 4; ++n) {
        int row = wc * 64 + n * 16 + lrow;
        bfr[n] = *(bv8*)((char*)Bs + row * 128 + (((ks * 4 + lkg) ^ (row & 7)) << 4));
      }
      #pragma unroll
      for (int m = 0; m < 4; ++m)
        #pragma unroll
        for (int n = 0; n < 4; ++n)
          acc[m][n] = MFMA16(af[m], bfr[n], acc[m][n]);
    }
    __syncthreads();
  }
  #pragma unroll
  for (int m = 0; m < 4; ++m) {
    int gr0 = row0 + wr * 64 + m * 16 + (lane >> 4) * 4;
    #pragma unroll
    for (int n = 0; n < 4; ++n) {
      int gc = col0 + wc * 64 + n * 16 + lrow;
      #pragma unroll
      for (int r = 0; r < 4; ++r) {
        int grow = gr0 + r;
        float vv = acc[m][n][r];
        if (EPI == 0) {
          ((bf16*)Cout)[(size_t)grow * N + gc] = __float2bfloat16(vv);
        } else if (EPI == 1) {
          ((float*)Cout)[(size_t)grow * N + gc] = vv;
        } else {
          int p = posq[grow];
          float add = (p >= 0) ? heavy[((size_t)((grow >> 12) * 512 + p)) * 1024 + gc]
                               : nullq[gc];
          ((float*)Cout)[(size_t)grow * N + gc] = vv + add;
        }
      }
    }
  }
}

// XCD-aware remap (bijective since gy % 8 == 0)
__device__ __forceinline__ void xcd_remap(int d, int gx, int& row0, int& col0) {
  int q = d >> 3;
  col0 = (q % gx) * 128;
  row0 = ((d & 7) + 8 * (q / gx)) * 128;
}

template<int EPI>
__global__ __launch_bounds__(256)
void gemm_bt(const bf16* __restrict__ A, const bf16* __restrict__ B, void* __restrict__ Cout,
             int N, int K,
             const int* __restrict__ posq, const float* __restrict__ heavy,
             const float* __restrict__ nullq) {
  __shared__ alignas(16) bf16 As[128 * 64];
  __shared__ alignas(16) bf16 Bs[128 * 64];
  int row0, col0;
  xcd_remap(blockIdx.y * gridDim.x + blockIdx.x, gridDim.x, row0, col0);
  gemm_core<EPI>(A, B, Cout, N, K, row0, col0, As, Bs, posq, heavy, nullq);
}

// ---------------- merged qkv GEMM (1536) + route_sel (8 blocks, prio-boosted) ----------------
__global__ __launch_bounds__(256)
void qkv_route_kernel(const bf16* __restrict__ ln, const bf16* __restrict__ Wqkv,
                      bf16* __restrict__ qkv,
                      const double* __restrict__ s_all, int* __restrict__ iq,
                      int* __restrict__ ikv, int* __restrict__ posq) {
  __shared__ __align__(16) char arena[34816];
  const int bid = blockIdx.x;
  const int tid = threadIdx.x;
  if (bid >= 8) {
    bf16* As = (bf16*)arena;
    bf16* Bs = (bf16*)(arena + 16384);
    int row0, col0;
    xcd_remap(bid - 8, 12, row0, col0);      // gx=12, gy=128
    gemm_core<0>(ln, Wqkv, qkv, 1536, 1024, row0, col0, As, Bs, nullptr, nullptr, nullptr);
  } else {
    // ---- routing: 50 fixed-point iters, 4 waves x 16 fp64/thread ----
    // setprio(1): these 4 waves are the launch straggler; favor them in
    // SIMD arbitration against co-resident GEMM waves (T5 regime).
    __builtin_amdgcn_s_setprio(1);
    const int route = bid >> 2, b = bid & 3;
    const double* s = s_all + route * 16384 + b * 4096;
    const double Kk = (route == 0) ? 576.0 : 1152.0;
    const int KSEL = (route == 0) ? 512 : 1024;
    const int lane = tid & 63, wid = tid >> 6;
    unsigned long long* keys = (unsigned long long*)arena;   // 32KB (fallback sort)
    int* scn = (int*)(arena + 32768);                        // 1KB
    double* red = (double*)(arena + 33792);                  // 4 doubles
    double sv[16];
    #pragma unroll
    for (int i = 0; i < 16; ++i) sv[i] = s[tid * 16 + i];
    double mx = sv[0];
    #pragma unroll
    for (int i = 1; i < 16; ++i) mx = fmax(mx, sv[i]);
    mx = blockReduceMaxD<4>(mx);
    double ev[16];
    #pragma unroll
    for (int i = 0; i < 16; ++i) ev[i] = exp(sv[i] - mx);
    double z = (4096.0 / Kk) * exp(-mx);     // iteration 1 closed form
    for (int it = 1; it < 50; ++it) {
      double t0 = 0.0, t1 = 0.0;
      #pragma unroll
      for (int i = 0; i < 16; i += 2) { t0 += fmin(ev[i], z); t1 += fmin(ev[i + 1], z); }
      double t = t0 + t1;
      #pragma unroll
      for (int m = 1; m < 64; m <<= 1) t += __shfl_xor(t, m, 64);
      if (lane == 0) red[wid] = t;
      __syncthreads();
      z = (red[0] + red[1] + red[2] + red[3]) / Kk;
      __syncthreads();
    }
    const double a = -mx - log(z);
    // final scores (fp32, reference semantics incl. rounding-to-1.0f ties)
    float scf[16]; int m16 = 0;
    #pragma unroll
    for (int i = 0; i < 16; ++i) {
      scf[i] = (float)exp(fmin(sv[i] + a, 0.0));
      m16 += (scf[i] == 1.0f) ? 1 : 0;
    }
    scn[tid] = m16;
    __syncthreads();
    for (int off = 1; off < 256; off <<= 1) {
      int v = (tid >= off) ? scn[tid - off] : 0;
      __syncthreads();
      scn[tid] += v;
      __syncthreads();
    }
    const int total = scn[255];
    const int excl = scn[tid] - m16;
    if (total >= KSEL) {
      int rk = excl;
      #pragma unroll
      for (int i = 0; i < 16; ++i) {
        if (scf[i] == 1.0f) {
          if (rk < KSEL) {
            int idx = tid * 16 + i;
            if (route == 0) { iq[b * 512 + rk] = idx; posq[b * 4096 + idx] = rk; }
            else            { ikv[b * 1024 + rk] = idx; }
          }
          rk++;
        }
      }
    } else {
      #pragma unroll
      for (int i = 0; i < 16; ++i) {
        unsigned bits = __float_as_uint(scf[i]);
        keys[tid * 16 + i] = ((unsigned long long)(~bits) << 32) | (unsigned long long)(tid * 16 + i);
      }
      for (int k = 2; k <= 4096; k <<= 1) {
        for (int j = k >> 1; j > 0; j >>= 1) {
          __syncthreads();
          for (int t = tid; t < 2048; t += 256) {
            int i2 = ((t & ~(j - 1)) << 1) | (t & (j - 1));
            int ip = i2 + j;
            unsigned long long av = keys[i2], bvv = keys[ip];
            bool up = ((i2 & k) == 0);
            if (up ? (av > bvv) : (av < bvv)) { keys[i2] = bvv; keys[ip] = av; }
          }
        }
      }
      __syncthreads();
      for (int j2 = tid; j2 < KSEL; j2 += 256) {
        int idx = (int)(keys[j2] & 0xFFFFFFFFull);
        if (route == 0) { iq[b * 512 + j2] = idx; posq[b * 4096 + idx] = j2; }
        else            { ikv[b * 1024 + j2] = idx; }
      }
    }
    __builtin_amdgcn_s_setprio(0);
  }
}

// ---------------- merged local attention (2048) + gather_rms (6144) ----------------
__global__ __launch_bounds__(256)
void la_gather_kernel(const bf16* __restrict__ qkv, bf16* __restrict__ olight,
                      const float* __restrict__ x, const float* __restrict__ gamma,
                      const int* __restrict__ iq, const int* __restrict__ ikv,
                      bf16* __restrict__ xq, bf16* __restrict__ xkv) {
  __shared__ bf16 Qs[64][72], Ks[64][72], Vts[64][72], Ps[64][72];
  const int tid = threadIdx.x;
  if (blockIdx.x < 2048) {
    const int w = blockIdx.x & 63, h = (blockIdx.x >> 6) & 7, b = blockIdx.x >> 9;
    const int lane = tid & 63, wv = tid >> 6;
    const int lrow = lane & 15, lkg = lane >> 4;
    {
      const size_t baseq = ((size_t)(b * 4096 + w * 64)) * 1536 + h * 64;
      #pragma unroll
      for (int v = 0; v < 2; ++v) {
        int vec = tid + v * 256; int i = vec >> 3, dd = (vec & 7) * 8;
        *(bv8*)&Qs[i][dd] = *(const bv8*)&qkv[baseq + (size_t)i * 1536 + dd];
      }
    }
    fv4 oacc[4];
    float m_run[4], l_run[4];
    #pragma unroll
    for (int n = 0; n < 4; ++n) oacc[n] = (fv4){0.f, 0.f, 0.f, 0.f};
    #pragma unroll
    for (int r = 0; r < 4; ++r) { m_run[r] = -INFINITY; l_run[r] = 0.f; }
    for (int c = 0; c < 3; ++c) {
      int sw = w - 1 + c;
      if (sw < 0 || sw >= 64) continue;
      __syncthreads();
      const size_t bkv = ((size_t)(b * 4096 + sw * 64)) * 1536 + h * 64;
      #pragma unroll
      for (int v = 0; v < 2; ++v) {
        int vec = tid + v * 256; int i = vec >> 3, dd = (vec & 7) * 8;
        *(bv8*)&Ks[i][dd] = *(const bv8*)&qkv[bkv + 512 + (size_t)i * 1536 + dd];
      }
      #pragma unroll
      for (int v = 0; v < 2; ++v) {
        int vec = tid + v * 256; int j = vec >> 3, d0 = (vec & 7) * 8;
        bv8 val = *(const bv8*)&qkv[bkv + 1024 + (size_t)j * 1536 + d0];
        #pragma unroll
        for (int i = 0; i < 8; ++i) Vts[d0 + i][j] = ((bf16*)&val)[i];
      }
      __syncthreads();
      fv4 sa[4];
      #pragma unroll
      for (int n = 0; n < 4; ++n) {
        sa[n] = (fv4){0.f, 0.f, 0.f, 0.f};
        #pragma unroll
        for (int ks = 0; ks < 2; ++ks) {
          bv8 aq = *(bv8*)&Qs[wv * 16 + lrow][lkg * 8 + ks * 32];
          bv8 bk = *(bv8*)&Ks[n * 16 + lrow][lkg * 8 + ks * 32];
          sa[n] = MFMA16(aq, bk, sa[n]);
        }
      }
      float mc[4];
      #pragma unroll
      for (int r = 0; r < 4; ++r) {
        #pragma unroll
        for (int n = 0; n < 4; ++n) sa[n][r] *= 0.125f;
        mc[r] = fmaxf(fmaxf(sa[0][r], sa[1][r]), fmaxf(sa[2][r], sa[3][r]));
      }
      #pragma unroll
      for (int m = 1; m < 16; m <<= 1)
        #pragma unroll
        for (int r = 0; r < 4; ++r) mc[r] = fmaxf(mc[r], __shfl_xor(mc[r], m, 64));
      float p[4][4], ls[4];
      #pragma unroll
      for (int r = 0; r < 4; ++r) {
        float mn = fmaxf(m_run[r], mc[r]);
        float scl = expf(m_run[r] - mn);
        ls[r] = 0.f;
        #pragma unroll
        for (int n = 0; n < 4; ++n) { p[n][r] = expf(sa[n][r] - mn); ls[r] += p[n][r]; }
        m_run[r] = mn;
        l_run[r] *= scl;
        #pragma unroll
        for (int n = 0; n < 4; ++n) oacc[n][r] *= scl;
      }
      #pragma unroll
      for (int m = 1; m < 16; m <<= 1)
        #pragma unroll
        for (int r = 0; r < 4; ++r) ls[r] += __shfl_xor(ls[r], m, 64);
      #pragma unroll
      for (int r = 0; r < 4; ++r) l_run[r] += ls[r];
      #pragma unroll
      for (int n = 0; n < 4; ++n)
        #pragma unroll
        for (int r = 0; r < 4; ++r)
          Ps[wv * 16 + lkg * 4 + r][n * 16 + lrow] = __float2bfloat16(p[n][r]);
      __syncthreads();
      #pragma unroll
      for (int n = 0; n < 4; ++n)
        #pragma unroll
        for (int ks = 0; ks < 2; ++ks) {
          bv8 ap = *(bv8*)&Ps[wv * 16 + lrow][lkg * 8 + ks * 32];
          bv8 bvv = *(bv8*)&Vts[n * 16 + lrow][lkg * 8 + ks * 32];
          oacc[n] = MFMA16(ap, bvv, oacc[n]);
        }
    }
    const size_t ob = ((size_t)(b * 4096 + w * 64 + wv * 16)) * 512 + h * 64;
    #pragma unroll
    for (int n = 0; n < 4; ++n)
      #pragma unroll
      for (int r = 0; r < 4; ++r) {
        int row = lkg * 4 + r;
        olight[ob + (size_t)row * 512 + n * 16 + lrow] = __float2bfloat16(oacc[n][r] / l_run[r]);
      }
  } else {
    const int gid = blockIdx.x - 2048;
    const float* src; bf16* dst;
    if (gid < 2048) {
      int b = gid >> 9, j = gid & 511;
      int tok = iq[b * 512 + j];
      src = x + ((size_t)(b * 4096 + tok)) * 1024;
      dst = xq + (size_t)gid * 1024;
    } else {
      int id = gid - 2048;
      int b = id >> 10, j = id & 1023;
      int tok = ikv[b * 1024 + j];
      src = x + ((size_t)(b * 4096 + tok)) * 1024;
      dst = xkv + (size_t)id * 1024;
    }
    float v4[4]; float ss = 0.f;
    #pragma unroll
    for (int i = 0; i < 4; ++i) { v4[i] = src[tid + i * 256]; ss += v4[i] * v4[i]; }
    ss = blockReduceSumF<4>(ss);
    const float nrm = fmaxf(sqrtf(ss), 1e-12f);
    const float scl = 32.0f / nrm;
    #pragma unroll
    for (int i = 0; i < 4; ++i) {
      int d = tid + i * 256;
      dst[d] = __float2bfloat16(v4[i] * scl * gamma[d]);
    }
  }
}

// ---------------- merged Wkv (256) + Wq (64) GEMMs ----------------
__global__ __launch_bounds__(256)
void wqkv_kernel(const bf16* __restrict__ xkv, const bf16* __restrict__ Wkv,
                 bf16* __restrict__ kvh,
                 const bf16* __restrict__ xq, const bf16* __restrict__ Wq,
                 bf16* __restrict__ qh) {
  __shared__ alignas(16) bf16 As[128 * 64];
  __shared__ alignas(16) bf16 Bs[128 * 64];
  const int bid = blockIdx.x;
  int row0, col0;
  if (bid < 256) {
    xcd_remap(bid, 8, row0, col0);          // Wkv: gx=8, gy=32
    gemm_core<0>(xkv, Wkv, kvh, 1024, 1024, row0, col0, As, Bs, nullptr, nullptr, nullptr);
  } else {
    xcd_remap(bid - 256, 4, row0, col0);    // Wq: gx=4, gy=16
    gemm_core<0>(xq, Wq, qh, 512, 1024, row0, col0, As, Bs, nullptr, nullptr, nullptr);
  }
}

// ---------------- heavy attention: 8-way split-K flash partials (bf16 partials) ----------------
// blockIdx: x=qt(8), y=h(8), z=b*8+s. split 0: tiles 0..2 (incl null);
// split s>0: tiles 2s+1 .. 2s+2. Total 3 + 7*2 = 17 tiles.
__global__ __launch_bounds__(256)
void heavy_attn_split_kernel(const bf16* __restrict__ qh, const bf16* __restrict__ kvh,
                             const float* __restrict__ nkv, bf16* __restrict__ o_part,
                             float* __restrict__ ml_part) {
  const int qt = blockIdx.x, h = blockIdx.y;
  const int b = blockIdx.z >> 3, s = blockIdx.z & 7;
  const int tid = threadIdx.x;
  const int lane = tid & 63, wv = tid >> 6;
  const int lrow = lane & 15, lkg = lane >> 4;
  __shared__ bf16 Qs[64][72], Ks[64][72], Vts[64][72], Ps[64][72];
  {
    const size_t baseq = ((size_t)(b * 512 + qt * 64)) * 512 + h * 64;
    #pragma unroll
    for (int v = 0; v < 2; ++v) {
      int vec = tid + v * 256; int i = vec >> 3, dd = (vec & 7) * 8;
      *(bv8*)&Qs[i][dd] = *(const bv8*)&qh[baseq + (size_t)i * 512 + dd];
    }
  }
  fv4 oacc[4];
  float m_run[4], l_run[4];
  #pragma unroll
  for (int n = 0; n < 4; ++n) oacc[n] = (fv4){0.f, 0.f, 0.f, 0.f};
  #pragma unroll
  for (int r = 0; r < 4; ++r) { m_run[r] = -INFINITY; l_run[r] = 0.f; }
  const int cs = (s == 0) ? 0 : (2 * s + 1);
  const int ce = 2 * s + 3;
  for (int c = cs; c < ce; ++c) {
    __syncthreads();
    #pragma unroll
    for (int v = 0; v < 2; ++v) {
      int vec = tid + v * 256; int j = vec >> 3, dd = (vec & 7) * 8;
      int kvg = c * 64 + j;
      bv8 val;
      if (kvg >= 1 && kvg <= 1024) {
        val = *(const bv8*)&kvh[((size_t)(b * 1024 + kvg - 1)) * 1024 + h * 128 + dd];
      } else if (kvg == 0) {
        #pragma unroll
        for (int t = 0; t < 8; ++t) ((bf16*)&val)[t] = __float2bfloat16(nkv[h * 64 + dd + t]);
      } else {
        #pragma unroll
        for (int t = 0; t < 8; ++t) ((short*)&val)[t] = 0;
      }
      *(bv8*)&Ks[j][dd] = val;
    }
    #pragma unroll
    for (int v = 0; v < 2; ++v) {
      int vec = tid + v * 256; int j = vec >> 3, d0 = (vec & 7) * 8;
      int kvg = c * 64 + j;
      if (kvg >= 1 && kvg <= 1024) {
        bv8 val = *(const bv8*)&kvh[((size_t)(b * 1024 + kvg - 1)) * 1024 + h * 128 + 64 + d0];
        #pragma unroll
        for (int i = 0; i < 8; ++i) Vts[d0 + i][j] = ((bf16*)&val)[i];
      } else if (kvg == 0) {
        #pragma unroll
        for (int i = 0; i < 8; ++i) Vts[d0 + i][j] = __float2bfloat16(nkv[512 + h * 64 + d0 + i]);
      } else {
        #pragma unroll
        for (int i = 0; i < 8; ++i) Vts[d0 + i][j] = __float2bfloat16(0.0f);
      }
    }
    __syncthreads();
    fv4 sa[4];
    #pragma unroll
    for (int n = 0; n < 4; ++n) {
      sa[n] = (fv4){0.f, 0.f, 0.f, 0.f};
      #pragma unroll
      for (int ks = 0; ks < 2; ++ks) {
        bv8 aq = *(bv8*)&Qs[wv * 16 + lrow][lkg * 8 + ks * 32];
        bv8 bk = *(bv8*)&Ks[n * 16 + lrow][lkg * 8 + ks * 32];
        sa[n] = MFMA16(aq, bk, sa[n]);
      }
    }
    float mc[4];
    #pragma unroll
    for (int r = 0; r < 4; ++r) {
      #pragma unroll
      for (int n = 0; n < 4; ++n) {
        sa[n][r] *= 0.125f;
        int kvg = c * 64 + n * 16 + lrow;
        if (kvg > 1024) sa[n][r] = -1e30f;
      }
      mc[r] = fmaxf(fmaxf(sa[0][r], sa[1][r]), fmaxf(sa[2][r], sa[3][r]));
    }
    #pragma unroll
    for (int m = 1; m < 16; m <<= 1)
      #pragma unroll
      for (int r = 0; r < 4; ++r) mc[r] = fmaxf(mc[r], __shfl_xor(mc[r], m, 64));
    float p[4][4], ls[4];
    #pragma unroll
    for (int r = 0; r < 4; ++r) {
      float mn = fmaxf(m_run[r], mc[r]);
      float scl = expf(m_run[r] - mn);
      ls[r] = 0.f;
      #pragma unroll
      for (int n = 0; n < 4; ++n) { p[n][r] = expf(sa[n][r] - mn); ls[r] += p[n][r]; }
      m_run[r] = mn;
      l_run[r] *= scl;
      #pragma unroll
      for (int n = 0; n < 4; ++n) oacc[n][r] *= scl;
    }
    #pragma unroll
    for (int m = 1; m < 16; m <<= 1)
      #pragma unroll
      for (int r = 0; r < 4; ++r) ls[r] += __shfl_xor(ls[r], m, 64);
    #pragma unroll
    for (int r = 0; r < 4; ++r) l_run[r] += ls[r];
    #pragma unroll
    for (int n = 0; n < 4; ++n)
      #pragma unroll
      for (int r = 0; r < 4; ++r)
        Ps[wv * 16 + lkg * 4 + r][n * 16 + lrow] = __float2bfloat16(p[n][r]);
    __syncthreads();
    #pragma unroll
    for (int n = 0; n < 4; ++n)
      #pragma unroll
      for (int ks = 0; ks < 2; ++ks) {
        bv8 ap = *(bv8*)&Ps[wv * 16 + lrow][lkg * 8 + ks * 32];
        bv8 bvv = *(bv8*)&Vts[n * 16 + lrow][lkg * 8 + ks * 32];
        oacc[n] = MFMA16(ap, bvv, oacc[n]);
      }
  }
  const int idx = (((s * 4 + b) * 8 + h) * 8 + qt);   // s<8, b<4 -> unique in [0,2048)
  bf16* ob = o_part + (size_t)idx * 4096;
  #pragma unroll
  for (int n = 0; n < 4; ++n)
    #pragma unroll
    for (int r = 0; r < 4; ++r) {
      int row = wv * 16 + lkg * 4 + r;
      ob[row * 64 + n * 16 + lrow] = __float2bfloat16(oacc[n][r]);
    }
  if (lrow == 0) {
    #pragma unroll
    for (int r = 0; r < 4; ++r) {
      int row = wv * 16 + lkg * 4 + r;
      ml_part[idx * 128 + row] = m_run[r];
      ml_part[idx * 128 + 64 + row] = l_run[r];
    }
  }
}

// ---------------- Wouth GEMM with fused 8-split combine in A-staging (BK=32 body) ----------------
__global__ __launch_bounds__(256)
void wouth_gemm_kernel(const bf16* __restrict__ o_part, const float* __restrict__ ml_part,
                       const bf16* __restrict__ B, float* __restrict__ Cout) {
  __shared__ alignas(16) bf16 As[128 * 32];
  __shared__ alignas(16) bf16 Bs[128 * 32];
  const int N = 1024, K = 512;
  int row0, col0;
  xcd_remap(blockIdx.y * gridDim.x + blockIdx.x, gridDim.x, row0, col0);  // gy=16 %8==0
  const int tid = threadIdx.x;
  const int lane = tid & 63, w = tid >> 6;
  const int wr = w >> 1, wc = w & 1;
  const int lrow = lane & 15, lk = (lane >> 4) * 8;
  fv4 acc[4][4];
  #pragma unroll
  for (int m = 0; m < 4; ++m)
    #pragma unroll
    for (int n = 0; n < 4; ++n) acc[m][n] = (fv4){0.f, 0.f, 0.f, 0.f};
  const int ob0 = w * 2048;
  for (int k0 = 0; k0 < K; k0 += 32) {
    #pragma unroll
    for (int t = 0; t < 2; ++t) {
      int ob = ob0 + t * 1024;
      int ofl = ob + lane * 16;         // per-lane LDS byte offset
      int r = ofl >> 6, c8 = ((ofl >> 4) & 3) * 8;
      int grow = row0 + r, k = k0 + c8;
      int b = grow >> 9, qrow = grow & 511;
      int qt = qrow >> 6, row_in = qrow & 63;
      int h = k >> 6, d0 = k & 63;
      // 8-split online combine
      float mstar = -INFINITY;
      float m[8], l[8];
      #pragma unroll
      for (int s = 0; s < 8; ++s) {
        int idx = (((s * 4 + b) * 8 + h) * 8 + qt);
        m[s] = ml_part[idx * 128 + row_in];
        l[s] = ml_part[idx * 128 + 64 + row_in];
        mstar = fmaxf(mstar, m[s]);
      }
      float ws[8]; float wsum = 0.f;
      #pragma unroll
      for (int s = 0; s < 8; ++s) { ws[s] = expf(m[s] - mstar); wsum += ws[s] * l[s]; }
      const float inv = 1.0f / wsum;
      float accv[8];
      #pragma unroll
      for (int j = 0; j < 8; ++j) accv[j] = 0.f;
      #pragma unroll
      for (int s = 0; s < 8; ++s) {
        int idx = (((s * 4 + b) * 8 + h) * 8 + qt);
        bv8 v = *(const bv8*)&o_part[(size_t)idx * 4096 + row_in * 64 + d0];
        #pragma unroll
        for (int j = 0; j < 8; ++j) accv[j] += ws[s] * __bfloat162float(((bf16*)&v)[j]);
      }
      bv8 o8;
      #pragma unroll
      for (int j = 0; j < 8; ++j) ((bf16*)&o8)[j] = __float2bfloat16(accv[j] * inv);
      *(bv8*)((char*)As + ofl) = o8;    // per-lane address
      GLOAD_LDS(B + (size_t)(col0 + r) * K + k0 + c8, (char*)Bs + ob);
    }
    __syncthreads();
    bv8 af[4], bfr[4];
    #pragma unroll
    for (int m2 = 0; m2 < 4; ++m2) af[m2] = *(bv8*)&As[(wr * 64 + m2 * 16 + lrow) * 32 + lk];
    #pragma unroll
    for (int n = 0; n < 4; ++n) bfr[n] = *(bv8*)&Bs[(wc * 64 + n * 16 + lrow) * 32 + lk];
    #pragma unroll
    for (int m2 = 0; m2 < 4; ++m2)
      #pragma unroll
      for (int n = 0; n < 4; ++n)
        acc[m2][n] = MFMA16(af[m2], bfr[n], acc[m2][n]);
    __syncthreads();
  }
  #pragma unroll
  for (int m2 = 0; m2 < 4; ++m2) {
    int gr0 = row0 + wr * 64 + m2 * 16 + (lane >> 4) * 4;
    #pragma unroll
    for (int n = 0; n < 4; ++n) {
      int gc = col0 + wc * 64 + n * 16 + lrow;
      #pragma unroll
      for (int r = 0; r < 4; ++r)
        Cout[(size_t)(gr0 + r) * N + gc] = acc[m2][n][r];
    }
  }
}

// ---------------- launcher ----------------
extern "C" void kernel_launch(void* const* d_in, const int* in_sizes, int n_in,
                              void* d_out, int out_size, void* d_ws, size_t ws_size,
                              hipStream_t stream) {
  (void)in_sizes; (void)n_in; (void)out_size; (void)ws_size;
  const float* x     = (const float*)d_in[0];
  const float* ln_w  = (const float*)d_in[1];
  const float* ln_b  = (const float*)d_in[2];
  const float* Wqkv  = (const float*)d_in[3];
  const float* Woutl = (const float*)d_in[4];
  const float* rtq   = (const float*)d_in[5];
  const float* rtkv  = (const float*)d_in[6];
  const float* gamma = (const float*)d_in[7];
  const float* Wq    = (const float*)d_in[8];
  const float* Wkv   = (const float*)d_in[9];
  const float* Wouth = (const float*)d_in[10];
  const float* nkv   = (const float*)d_in[11];
  const float* nq    = (const float*)d_in[12];
  float* out = (float*)d_out;

  char* ws = (char*)d_ws;
  size_t off = 0;
  auto alloc = [&](size_t bytes) -> void* {
    void* p = ws + off;
    off = (off + bytes + 255) & ~(size_t)255;
    return p;
  };
  bf16* ln_bf    = (bf16*)alloc(16384ull * 1024 * 2);
  bf16* qkv_bf   = (bf16*)alloc(16384ull * 1536 * 2);
  bf16* ol_bf    = (bf16*)alloc(16384ull * 512 * 2);
  bf16* Wqkv_bf  = (bf16*)alloc(1536ull * 1024 * 2);
  bf16* Woutl_bf = (bf16*)alloc(1024ull * 512 * 2);
  bf16* Wq_bf    = (bf16*)alloc(512ull * 1024 * 2);
  bf16* Wkv_bf   = (bf16*)alloc(1024ull * 1024 * 2);
  bf16* Wouth_bf = (bf16*)alloc(1024ull * 512 * 2);
  double* s_d    = (double*)alloc(32768ull * 8);
  int* iq        = (int*)alloc(2048ull * 4);
  int* ikv       = (int*)alloc(4096ull * 4);
  int* posq      = (int*)alloc(16384ull * 4);
  bf16* xq_bf    = (bf16*)alloc(2048ull * 1024 * 2);
  bf16* xkv_bf   = (bf16*)alloc(4096ull * 1024 * 2);
  bf16* qh_bf    = (bf16*)alloc(2048ull * 512 * 2);
  bf16* kvh_bf   = (bf16*)alloc(4096ull * 1024 * 2);
  float* heavy_f = (float*)alloc(2048ull * 1024 * 4);
  bf16* o_part   = (bf16*)alloc(8192ull * 4096 * 2);   // 2048 tiles x 64x64 bf16
  float* ml_part = (float*)alloc(8192ull * 128 * 4);

  // 1. prep: LN+sdot | weight casts | posq init
  prep_kernel<<<18448, 256, 0, stream>>>(x, ln_w, ln_b, rtq, rtkv, ln_bf, s_d,
                                         Wqkv, Woutl, Wq, Wkv, Wouth,
                                         Wqkv_bf, Woutl_bf, Wq_bf, Wkv_bf, Wouth_bf,
                                         posq);

  // 2. qkv projection GEMM (1536) + routing (8, dispatched first, prio-boosted)
  qkv_route_kernel<<<1544, 256, 0, stream>>>(ln_bf, Wqkv_bf, qkv_bf,
                                             s_d, iq, ikv, posq);

  // 3. local attention + heavy-path gather (merged)
  la_gather_kernel<<<8192, 256, 0, stream>>>(qkv_bf, ol_bf, x, gamma, iq, ikv, xq_bf, xkv_bf);

  // 4. heavy projections (merged Wkv + Wq)
  wqkv_kernel<<<320, 256, 0, stream>>>(xkv_bf, Wkv_bf, kvh_bf, xq_bf, Wq_bf, qh_bf);

  // 5. heavy attention 8-way split-K partials
  heavy_attn_split_kernel<<<dim3(8, 8, 32), 256, 0, stream>>>(qh_bf, kvh_bf, nkv, o_part, ml_part);

  // 6. Wouth GEMM with fused 8-split combine
  wouth_gemm_kernel<<<dim3(8, 16), 256, 0, stream>>>(o_part, ml_part, Wouth_bf, heavy_f);

  // 7. light output GEMM + fused combine (heavy scatter / null_q) -> d_out
  gemm_bt<2><<<dim3(8, 128), 256, 0, stream>>>(ol_bf, Woutl_bf, out, 1024, 512,
                                               posq, heavy_f, nq);
}

// Round 16
// 272.726 us; speedup vs baseline: 1.1140x; 1.1140x over previous
//
#include <hip/hip_runtime.h>
#include <hip/hip_bf16.h>

typedef __attribute__((ext_vector_type(8))) short bv8;
typedef __attribute__((ext_vector_type(4))) float fv4;
typedef __hip_bfloat16 bf16;

#define MFMA16(a,b,c) __builtin_amdgcn_mfma_f32_16x16x32_bf16((a),(b),(c),0,0,0)
#define GLOAD_LDS(gp, lp) __builtin_amdgcn_global_load_lds( \
    (const __attribute__((address_space(1))) void*)(gp), \
    (__attribute__((address_space(3))) void*)(lp), 16, 0, 0)

// ---------------- block reduce helpers ----------------
template<int NW>
__device__ __forceinline__ float blockReduceSumF(float v) {
  #pragma unroll
  for (int m = 1; m < 64; m <<= 1) v += __shfl_xor(v, m, 64);
  __shared__ float sm[NW];
  if ((threadIdx.x & 63) == 0) sm[threadIdx.x >> 6] = v;
  __syncthreads();
  float t = 0.f;
  #pragma unroll
  for (int i = 0; i < NW; ++i) t += sm[i];
  __syncthreads();
  return t;
}

template<int NW>
__device__ __forceinline__ double blockReduceMaxD(double v) {
  #pragma unroll
  for (int m = 1; m < 64; m <<= 1) v = fmax(v, __shfl_xor(v, m, 64));
  __shared__ double sm[NW];
  if ((threadIdx.x & 63) == 0) sm[threadIdx.x >> 6] = v;
  __syncthreads();
  double t = sm[0];
  #pragma unroll
  for (int i = 1; i < NW; ++i) t = fmax(t, sm[i]);
  __syncthreads();
  return t;
}

// ---------------- prep: fused LN+sdot (16384) | weight cast (2048) | posq init (16) ----------------
__global__ __launch_bounds__(256)
void prep_kernel(const float* __restrict__ x, const float* __restrict__ lnw,
                 const float* __restrict__ lnb, const float* __restrict__ rtq,
                 const float* __restrict__ rtkv, bf16* __restrict__ lnout,
                 double* __restrict__ s,
                 const float* __restrict__ a0, const float* __restrict__ a1,
                 const float* __restrict__ a2, const float* __restrict__ a3,
                 const float* __restrict__ a4,
                 bf16* __restrict__ b0, bf16* __restrict__ b1, bf16* __restrict__ b2,
                 bf16* __restrict__ b3, bf16* __restrict__ b4,
                 int* __restrict__ posq) {
  const int bid = blockIdx.x;
  if (bid < 16384) {
    const int r = bid;
    const float* xr = x + (size_t)r * 1024;
    float v4[4]; float ssum = 0.f;
    double dq = 0.0, dk = 0.0;
    #pragma unroll
    for (int i = 0; i < 4; ++i) {
      int d = threadIdx.x + i * 256;
      float v = xr[d];
      v4[i] = v; ssum += v;
      dq += (double)v * (double)rtq[d];
      dk += (double)v * (double)rtkv[d];
    }
    ssum = blockReduceSumF<4>(ssum);
    const float mean = ssum * (1.0f / 1024.0f);
    float vs = 0.f;
    #pragma unroll
    for (int i = 0; i < 4; ++i) { float d = v4[i] - mean; vs += d * d; }
    vs = blockReduceSumF<4>(vs);
    const float rstd = 1.0f / sqrtf(vs * (1.0f / 1024.0f) + 1e-5f);
    #pragma unroll
    for (int m = 1; m < 64; m <<= 1) { dq += __shfl_xor(dq, m, 64); dk += __shfl_xor(dk, m, 64); }
    __shared__ double smq[4], smk[4];
    if ((threadIdx.x & 63) == 0) { smq[threadIdx.x >> 6] = dq; smk[threadIdx.x >> 6] = dk; }
    __syncthreads();
    if (threadIdx.x == 0) {
      s[r] = smq[0] + smq[1] + smq[2] + smq[3];
      s[16384 + r] = smk[0] + smk[1] + smk[2] + smk[3];
    }
    bf16* orow = lnout + (size_t)r * 1024;
    #pragma unroll
    for (int i = 0; i < 4; ++i) {
      int d = threadIdx.x + i * 256;
      orow[d] = __float2bfloat16((v4[i] - mean) * rstd * lnw[d] + lnb[d]);
    }
  } else if (bid < 18432) {
    size_t g = ((size_t)(bid - 16384) * 256 + threadIdx.x) * 8;
    const float* src; bf16* dst; size_t off;
    if (g < 1572864)      { src = a0; dst = b0; off = g; }
    else if (g < 2097152) { src = a1; dst = b1; off = g - 1572864; }
    else if (g < 2621440) { src = a2; dst = b2; off = g - 2097152; }
    else if (g < 3670016) { src = a3; dst = b3; off = g - 2621440; }
    else                  { src = a4; dst = b4; off = g - 3670016; }
    float4 v0 = *(const float4*)(src + off);
    float4 v1 = *(const float4*)(src + off + 4);
    bv8 o;
    ((bf16*)&o)[0] = __float2bfloat16(v0.x); ((bf16*)&o)[1] = __float2bfloat16(v0.y);
    ((bf16*)&o)[2] = __float2bfloat16(v0.z); ((bf16*)&o)[3] = __float2bfloat16(v0.w);
    ((bf16*)&o)[4] = __float2bfloat16(v1.x); ((bf16*)&o)[5] = __float2bfloat16(v1.y);
    ((bf16*)&o)[6] = __float2bfloat16(v1.z); ((bf16*)&o)[7] = __float2bfloat16(v1.w);
    *(bv8*)(dst + off) = o;
  } else {
    int i0 = (bid - 18432) * 1024 + threadIdx.x * 4;
    posq[i0] = -1; posq[i0 + 1] = -1; posq[i0 + 2] = -1; posq[i0 + 3] = -1;
  }
}

// ---------------- GEMM 128x128 core, BK=64 with st-XOR swizzle ----------------
// EPI: 0 = bf16 store, 1 = f32 store, 2 = f32 store + combine (light + heavy/null_q)
template<int EPI>
__device__ __forceinline__ void gemm_core(
    const bf16* __restrict__ A, const bf16* __restrict__ B, void* __restrict__ Cout,
    int N, int K, int row0, int col0, bf16* As, bf16* Bs,
    const int* __restrict__ posq, const float* __restrict__ heavy,
    const float* __restrict__ nullq) {
  const int tid = threadIdx.x;
  const int lane = tid & 63, w = tid >> 6;
  const int wr = w >> 1, wc = w & 1;
  const int lrow = lane & 15, lkg = lane >> 4;
  fv4 acc[4][4];
  #pragma unroll
  for (int m = 0; m < 4; ++m)
    #pragma unroll
    for (int n = 0; n < 4; ++n) acc[m][n] = (fv4){0.f, 0.f, 0.f, 0.f};
  const int ob0 = w * 1024;
  for (int k0 = 0; k0 < K; k0 += 64) {
    #pragma unroll
    for (int t = 0; t < 4; ++t) {
      int ob = t * 4096 + ob0;
      int byteL = ob + lane * 16;
      int r = byteL >> 7;
      int cU = ((byteL >> 4) & 7) ^ (r & 7);
      GLOAD_LDS(A + (size_t)(row0 + r) * K + k0 + cU * 8, (char*)As + ob);
      GLOAD_LDS(B + (size_t)(col0 + r) * K + k0 + cU * 8, (char*)Bs + ob);
    }
    __syncthreads();
    #pragma unroll
    for (int ks = 0; ks < 2; ++ks) {
      bv8 af[4], bfr[4];
      #pragma unroll
      for (int m = 0; m < 4; ++m) {
        int row = wr * 64 + m * 16 + lrow;
        af[m] = *(bv8*)((char*)As + row * 128 + (((ks * 4 + lkg) ^ (row & 7)) << 4));
      }
      #pragma unroll
      for (int n = 0; n < 4; ++n) {
        int row = wc * 64 + n * 16 + lrow;
        bfr[n] = *(bv8*)((char*)Bs + row * 128 + (((ks * 4 + lkg) ^ (row & 7)) << 4));
      }
      #pragma unroll
      for (int m = 0; m < 4; ++m)
        #pragma unroll
        for (int n = 0; n < 4; ++n)
          acc[m][n] = MFMA16(af[m], bfr[n], acc[m][n]);
    }
    __syncthreads();
  }
  #pragma unroll
  for (int m = 0; m < 4; ++m) {
    int gr0 = row0 + wr * 64 + m * 16 + (lane >> 4) * 4;
    #pragma unroll
    for (int n = 0; n < 4; ++n) {
      int gc = col0 + wc * 64 + n * 16 + lrow;
      #pragma unroll
      for (int r = 0; r < 4; ++r) {
        int grow = gr0 + r;
        float vv = acc[m][n][r];
        if (EPI == 0) {
          ((bf16*)Cout)[(size_t)grow * N + gc] = __float2bfloat16(vv);
        } else if (EPI == 1) {
          ((float*)Cout)[(size_t)grow * N + gc] = vv;
        } else {
          int p = posq[grow];
          float add = (p >= 0) ? heavy[((size_t)((grow >> 12) * 512 + p)) * 1024 + gc]
                               : nullq[gc];
          ((float*)Cout)[(size_t)grow * N + gc] = vv + add;
        }
      }
    }
  }
}

// XCD-aware remap (bijective since gy % 8 == 0)
__device__ __forceinline__ void xcd_remap(int d, int gx, int& row0, int& col0) {
  int q = d >> 3;
  col0 = (q % gx) * 128;
  row0 = ((d & 7) + 8 * (q / gx)) * 128;
}

template<int EPI>
__global__ __launch_bounds__(256)
void gemm_bt(const bf16* __restrict__ A, const bf16* __restrict__ B, void* __restrict__ Cout,
             int N, int K,
             const int* __restrict__ posq, const float* __restrict__ heavy,
             const float* __restrict__ nullq) {
  __shared__ alignas(16) bf16 As[128 * 64];
  __shared__ alignas(16) bf16 Bs[128 * 64];
  int row0, col0;
  xcd_remap(blockIdx.y * gridDim.x + blockIdx.x, gridDim.x, row0, col0);
  gemm_core<EPI>(A, B, Cout, N, K, row0, col0, As, Bs, posq, heavy, nullq);
}

// ---------------- merged qkv GEMM (1536) + route_sel (8 blocks, dispatched first) ----------------
__global__ __launch_bounds__(256)
void qkv_route_kernel(const bf16* __restrict__ ln, const bf16* __restrict__ Wqkv,
                      bf16* __restrict__ qkv,
                      const double* __restrict__ s_all, int* __restrict__ iq,
                      int* __restrict__ ikv, int* __restrict__ posq) {
  __shared__ __align__(16) char arena[34816];
  const int bid = blockIdx.x;
  const int tid = threadIdx.x;
  if (bid >= 8) {
    bf16* As = (bf16*)arena;
    bf16* Bs = (bf16*)(arena + 16384);
    int row0, col0;
    xcd_remap(bid - 8, 12, row0, col0);      // gx=12, gy=128
    gemm_core<0>(ln, Wqkv, qkv, 1536, 1024, row0, col0, As, Bs, nullptr, nullptr, nullptr);
  } else {
    // ---- routing: 50 fixed-point iters, 4 waves x 16 fp64/thread ----
    const int route = bid >> 2, b = bid & 3;
    const double* s = s_all + route * 16384 + b * 4096;
    const double Kk = (route == 0) ? 576.0 : 1152.0;
    const int KSEL = (route == 0) ? 512 : 1024;
    const int lane = tid & 63, wid = tid >> 6;
    unsigned long long* keys = (unsigned long long*)arena;   // 32KB (fallback sort)
    int* scn = (int*)(arena + 32768);                        // 1KB
    double* red = (double*)(arena + 33792);                  // 4 doubles
    double sv[16];
    #pragma unroll
    for (int i = 0; i < 16; ++i) sv[i] = s[tid * 16 + i];
    double mx = sv[0];
    #pragma unroll
    for (int i = 1; i < 16; ++i) mx = fmax(mx, sv[i]);
    mx = blockReduceMaxD<4>(mx);
    double ev[16];
    #pragma unroll
    for (int i = 0; i < 16; ++i) ev[i] = exp(sv[i] - mx);
    double z = (4096.0 / Kk) * exp(-mx);     // iteration 1 closed form
    for (int it = 1; it < 50; ++it) {
      double t0 = 0.0, t1 = 0.0;
      #pragma unroll
      for (int i = 0; i < 16; i += 2) { t0 += fmin(ev[i], z); t1 += fmin(ev[i + 1], z); }
      double t = t0 + t1;
      #pragma unroll
      for (int m = 1; m < 64; m <<= 1) t += __shfl_xor(t, m, 64);
      if (lane == 0) red[wid] = t;
      __syncthreads();
      z = (red[0] + red[1] + red[2] + red[3]) / Kk;
      __syncthreads();
    }
    const double a = -mx - log(z);
    // final scores (fp32, reference semantics incl. rounding-to-1.0f ties)
    float scf[16]; int m16 = 0;
    #pragma unroll
    for (int i = 0; i < 16; ++i) {
      scf[i] = (float)exp(fmin(sv[i] + a, 0.0));
      m16 += (scf[i] == 1.0f) ? 1 : 0;
    }
    scn[tid] = m16;
    __syncthreads();
    for (int off = 1; off < 256; off <<= 1) {
      int v = (tid >= off) ? scn[tid - off] : 0;
      __syncthreads();
      scn[tid] += v;
      __syncthreads();
    }
    const int total = scn[255];
    const int excl = scn[tid] - m16;
    if (total >= KSEL) {
      int rk = excl;
      #pragma unroll
      for (int i = 0; i < 16; ++i) {
        if (scf[i] == 1.0f) {
          if (rk < KSEL) {
            int idx = tid * 16 + i;
            if (route == 0) { iq[b * 512 + rk] = idx; posq[b * 4096 + idx] = rk; }
            else            { ikv[b * 1024 + rk] = idx; }
          }
          rk++;
        }
      }
    } else {
      #pragma unroll
      for (int i = 0; i < 16; ++i) {
        unsigned bits = __float_as_uint(scf[i]);
        keys[tid * 16 + i] = ((unsigned long long)(~bits) << 32) | (unsigned long long)(tid * 16 + i);
      }
      for (int k = 2; k <= 4096; k <<= 1) {
        for (int j = k >> 1; j > 0; j >>= 1) {
          __syncthreads();
          for (int t = tid; t < 2048; t += 256) {
            int i2 = ((t & ~(j - 1)) << 1) | (t & (j - 1));
            int ip = i2 + j;
            unsigned long long av = keys[i2], bvv = keys[ip];
            bool up = ((i2 & k) == 0);
            if (up ? (av > bvv) : (av < bvv)) { keys[i2] = bvv; keys[ip] = av; }
          }
        }
      }
      __syncthreads();
      for (int j2 = tid; j2 < KSEL; j2 += 256) {
        int idx = (int)(keys[j2] & 0xFFFFFFFFull);
        if (route == 0) { iq[b * 512 + j2] = idx; posq[b * 4096 + idx] = j2; }
        else            { ikv[b * 1024 + j2] = idx; }
      }
    }
  }
}

// ---------------- merged local attention (2048) + gather_rms (6144) ----------------
__global__ __launch_bounds__(256)
void la_gather_kernel(const bf16* __restrict__ qkv, bf16* __restrict__ olight,
                      const float* __restrict__ x, const float* __restrict__ gamma,
                      const int* __restrict__ iq, const int* __restrict__ ikv,
                      bf16* __restrict__ xq, bf16* __restrict__ xkv) {
  __shared__ bf16 Qs[64][72], Ks[64][72], Vts[64][72], Ps[64][72];
  const int tid = threadIdx.x;
  if (blockIdx.x < 2048) {
    const int w = blockIdx.x & 63, h = (blockIdx.x >> 6) & 7, b = blockIdx.x >> 9;
    const int lane = tid & 63, wv = tid >> 6;
    const int lrow = lane & 15, lkg = lane >> 4;
    {
      const size_t baseq = ((size_t)(b * 4096 + w * 64)) * 1536 + h * 64;
      #pragma unroll
      for (int v = 0; v < 2; ++v) {
        int vec = tid + v * 256; int i = vec >> 3, dd = (vec & 7) * 8;
        *(bv8*)&Qs[i][dd] = *(const bv8*)&qkv[baseq + (size_t)i * 1536 + dd];
      }
    }
    fv4 oacc[4];
    float m_run[4], l_run[4];
    #pragma unroll
    for (int n = 0; n < 4; ++n) oacc[n] = (fv4){0.f, 0.f, 0.f, 0.f};
    #pragma unroll
    for (int r = 0; r < 4; ++r) { m_run[r] = -INFINITY; l_run[r] = 0.f; }
    for (int c = 0; c < 3; ++c) {
      int sw = w - 1 + c;
      if (sw < 0 || sw >= 64) continue;
      __syncthreads();
      const size_t bkv = ((size_t)(b * 4096 + sw * 64)) * 1536 + h * 64;
      #pragma unroll
      for (int v = 0; v < 2; ++v) {
        int vec = tid + v * 256; int i = vec >> 3, dd = (vec & 7) * 8;
        *(bv8*)&Ks[i][dd] = *(const bv8*)&qkv[bkv + 512 + (size_t)i * 1536 + dd];
      }
      #pragma unroll
      for (int v = 0; v < 2; ++v) {
        int vec = tid + v * 256; int j = vec >> 3, d0 = (vec & 7) * 8;
        bv8 val = *(const bv8*)&qkv[bkv + 1024 + (size_t)j * 1536 + d0];
        #pragma unroll
        for (int i = 0; i < 8; ++i) Vts[d0 + i][j] = ((bf16*)&val)[i];
      }
      __syncthreads();
      fv4 sa[4];
      #pragma unroll
      for (int n = 0; n < 4; ++n) {
        sa[n] = (fv4){0.f, 0.f, 0.f, 0.f};
        #pragma unroll
        for (int ks = 0; ks < 2; ++ks) {
          bv8 aq = *(bv8*)&Qs[wv * 16 + lrow][lkg * 8 + ks * 32];
          bv8 bk = *(bv8*)&Ks[n * 16 + lrow][lkg * 8 + ks * 32];
          sa[n] = MFMA16(aq, bk, sa[n]);
        }
      }
      float mc[4];
      #pragma unroll
      for (int r = 0; r < 4; ++r) {
        #pragma unroll
        for (int n = 0; n < 4; ++n) sa[n][r] *= 0.125f;
        mc[r] = fmaxf(fmaxf(sa[0][r], sa[1][r]), fmaxf(sa[2][r], sa[3][r]));
      }
      #pragma unroll
      for (int m = 1; m < 16; m <<= 1)
        #pragma unroll
        for (int r = 0; r < 4; ++r) mc[r] = fmaxf(mc[r], __shfl_xor(mc[r], m, 64));
      float p[4][4], ls[4];
      #pragma unroll
      for (int r = 0; r < 4; ++r) {
        float mn = fmaxf(m_run[r], mc[r]);
        float scl = expf(m_run[r] - mn);
        ls[r] = 0.f;
        #pragma unroll
        for (int n = 0; n < 4; ++n) { p[n][r] = expf(sa[n][r] - mn); ls[r] += p[n][r]; }
        m_run[r] = mn;
        l_run[r] *= scl;
        #pragma unroll
        for (int n = 0; n < 4; ++n) oacc[n][r] *= scl;
      }
      #pragma unroll
      for (int m = 1; m < 16; m <<= 1)
        #pragma unroll
        for (int r = 0; r < 4; ++r) ls[r] += __shfl_xor(ls[r], m, 64);
      #pragma unroll
      for (int r = 0; r < 4; ++r) l_run[r] += ls[r];
      #pragma unroll
      for (int n = 0; n < 4; ++n)
        #pragma unroll
        for (int r = 0; r < 4; ++r)
          Ps[wv * 16 + lkg * 4 + r][n * 16 + lrow] = __float2bfloat16(p[n][r]);
      __syncthreads();
      #pragma unroll
      for (int n = 0; n < 4; ++n)
        #pragma unroll
        for (int ks = 0; ks < 2; ++ks) {
          bv8 ap = *(bv8*)&Ps[wv * 16 + lrow][lkg * 8 + ks * 32];
          bv8 bvv = *(bv8*)&Vts[n * 16 + lrow][lkg * 8 + ks * 32];
          oacc[n] = MFMA16(ap, bvv, oacc[n]);
        }
    }
    const size_t ob = ((size_t)(b * 4096 + w * 64 + wv * 16)) * 512 + h * 64;
    #pragma unroll
    for (int n = 0; n < 4; ++n)
      #pragma unroll
      for (int r = 0; r < 4; ++r) {
        int row = lkg * 4 + r;
        olight[ob + (size_t)row * 512 + n * 16 + lrow] = __float2bfloat16(oacc[n][r] / l_run[r]);
      }
  } else {
    const int gid = blockIdx.x - 2048;
    const float* src; bf16* dst;
    if (gid < 2048) {
      int b = gid >> 9, j = gid & 511;
      int tok = iq[b * 512 + j];
      src = x + ((size_t)(b * 4096 + tok)) * 1024;
      dst = xq + (size_t)gid * 1024;
    } else {
      int id = gid - 2048;
      int b = id >> 10, j = id & 1023;
      int tok = ikv[b * 1024 + j];
      src = x + ((size_t)(b * 4096 + tok)) * 1024;
      dst = xkv + (size_t)id * 1024;
    }
    float v4[4]; float ss = 0.f;
    #pragma unroll
    for (int i = 0; i < 4; ++i) { v4[i] = src[tid + i * 256]; ss += v4[i] * v4[i]; }
    ss = blockReduceSumF<4>(ss);
    const float nrm = fmaxf(sqrtf(ss), 1e-12f);
    const float scl = 32.0f / nrm;
    #pragma unroll
    for (int i = 0; i < 4; ++i) {
      int d = tid + i * 256;
      dst[d] = __float2bfloat16(v4[i] * scl * gamma[d]);
    }
  }
}

// ---------------- merged Wkv (256) + Wq (64) GEMMs ----------------
__global__ __launch_bounds__(256)
void wqkv_kernel(const bf16* __restrict__ xkv, const bf16* __restrict__ Wkv,
                 bf16* __restrict__ kvh,
                 const bf16* __restrict__ xq, const bf16* __restrict__ Wq,
                 bf16* __restrict__ qh) {
  __shared__ alignas(16) bf16 As[128 * 64];
  __shared__ alignas(16) bf16 Bs[128 * 64];
  const int bid = blockIdx.x;
  int row0, col0;
  if (bid < 256) {
    xcd_remap(bid, 8, row0, col0);          // Wkv: gx=8, gy=32
    gemm_core<0>(xkv, Wkv, kvh, 1024, 1024, row0, col0, As, Bs, nullptr, nullptr, nullptr);
  } else {
    xcd_remap(bid - 256, 4, row0, col0);    // Wq: gx=4, gy=16
    gemm_core<0>(xq, Wq, qh, 512, 1024, row0, col0, As, Bs, nullptr, nullptr, nullptr);
  }
}

// ---------------- heavy attention: split-K flash partials (bf16 partials) ----------------
__global__ __launch_bounds__(256)
void heavy_attn_split_kernel(const bf16* __restrict__ qh, const bf16* __restrict__ kvh,
                             const float* __restrict__ nkv, bf16* __restrict__ o_part,
                             float* __restrict__ ml_part) {
  const int qt = blockIdx.x, h = blockIdx.y;
  const int b = blockIdx.z >> 2, s = blockIdx.z & 3;
  const int tid = threadIdx.x;
  const int lane = tid & 63, wv = tid >> 6;
  const int lrow = lane & 15, lkg = lane >> 4;
  __shared__ bf16 Qs[64][72], Ks[64][72], Vts[64][72], Ps[64][72];
  {
    const size_t baseq = ((size_t)(b * 512 + qt * 64)) * 512 + h * 64;
    #pragma unroll
    for (int v = 0; v < 2; ++v) {
      int vec = tid + v * 256; int i = vec >> 3, dd = (vec & 7) * 8;
      *(bv8*)&Qs[i][dd] = *(const bv8*)&qh[baseq + (size_t)i * 512 + dd];
    }
  }
  fv4 oacc[4];
  float m_run[4], l_run[4];
  #pragma unroll
  for (int n = 0; n < 4; ++n) oacc[n] = (fv4){0.f, 0.f, 0.f, 0.f};
  #pragma unroll
  for (int r = 0; r < 4; ++r) { m_run[r] = -INFINITY; l_run[r] = 0.f; }
  const int cs = (s == 0) ? 0 : (s * 4 + 1);
  const int ce = s * 4 + 5;
  for (int c = cs; c < ce; ++c) {
    __syncthreads();
    #pragma unroll
    for (int v = 0; v < 2; ++v) {
      int vec = tid + v * 256; int j = vec >> 3, dd = (vec & 7) * 8;
      int kvg = c * 64 + j;
      bv8 val;
      if (kvg >= 1 && kvg <= 1024) {
        val = *(const bv8*)&kvh[((size_t)(b * 1024 + kvg - 1)) * 1024 + h * 128 + dd];
      } else if (kvg == 0) {
        #pragma unroll
        for (int t = 0; t < 8; ++t) ((bf16*)&val)[t] = __float2bfloat16(nkv[h * 64 + dd + t]);
      } else {
        #pragma unroll
        for (int t = 0; t < 8; ++t) ((short*)&val)[t] = 0;
      }
      *(bv8*)&Ks[j][dd] = val;
    }
    #pragma unroll
    for (int v = 0; v < 2; ++v) {
      int vec = tid + v * 256; int j = vec >> 3, d0 = (vec & 7) * 8;
      int kvg = c * 64 + j;
      if (kvg >= 1 && kvg <= 1024) {
        bv8 val = *(const bv8*)&kvh[((size_t)(b * 1024 + kvg - 1)) * 1024 + h * 128 + 64 + d0];
        #pragma unroll
        for (int i = 0; i < 8; ++i) Vts[d0 + i][j] = ((bf16*)&val)[i];
      } else if (kvg == 0) {
        #pragma unroll
        for (int i = 0; i < 8; ++i) Vts[d0 + i][j] = __float2bfloat16(nkv[512 + h * 64 + d0 + i]);
      } else {
        #pragma unroll
        for (int i = 0; i < 8; ++i) Vts[d0 + i][j] = __float2bfloat16(0.0f);
      }
    }
    __syncthreads();
    fv4 sa[4];
    #pragma unroll
    for (int n = 0; n < 4; ++n) {
      sa[n] = (fv4){0.f, 0.f, 0.f, 0.f};
      #pragma unroll
      for (int ks = 0; ks < 2; ++ks) {
        bv8 aq = *(bv8*)&Qs[wv * 16 + lrow][lkg * 8 + ks * 32];
        bv8 bk = *(bv8*)&Ks[n * 16 + lrow][lkg * 8 + ks * 32];
        sa[n] = MFMA16(aq, bk, sa[n]);
      }
    }
    float mc[4];
    #pragma unroll
    for (int r = 0; r < 4; ++r) {
      #pragma unroll
      for (int n = 0; n < 4; ++n) {
        sa[n][r] *= 0.125f;
        int kvg = c * 64 + n * 16 + lrow;
        if (kvg > 1024) sa[n][r] = -1e30f;
      }
      mc[r] = fmaxf(fmaxf(sa[0][r], sa[1][r]), fmaxf(sa[2][r], sa[3][r]));
    }
    #pragma unroll
    for (int m = 1; m < 16; m <<= 1)
      #pragma unroll
      for (int r = 0; r < 4; ++r) mc[r] = fmaxf(mc[r], __shfl_xor(mc[r], m, 64));
    float p[4][4], ls[4];
    #pragma unroll
    for (int r = 0; r < 4; ++r) {
      float mn = fmaxf(m_run[r], mc[r]);
      float scl = expf(m_run[r] - mn);
      ls[r] = 0.f;
      #pragma unroll
      for (int n = 0; n < 4; ++n) { p[n][r] = expf(sa[n][r] - mn); ls[r] += p[n][r]; }
      m_run[r] = mn;
      l_run[r] *= scl;
      #pragma unroll
      for (int n = 0; n < 4; ++n) oacc[n][r] *= scl;
    }
    #pragma unroll
    for (int m = 1; m < 16; m <<= 1)
      #pragma unroll
      for (int r = 0; r < 4; ++r) ls[r] += __shfl_xor(ls[r], m, 64);
    #pragma unroll
    for (int r = 0; r < 4; ++r) l_run[r] += ls[r];
    #pragma unroll
    for (int n = 0; n < 4; ++n)
      #pragma unroll
      for (int r = 0; r < 4; ++r)
        Ps[wv * 16 + lkg * 4 + r][n * 16 + lrow] = __float2bfloat16(p[n][r]);
    __syncthreads();
    #pragma unroll
    for (int n = 0; n < 4; ++n)
      #pragma unroll
      for (int ks = 0; ks < 2; ++ks) {
        bv8 ap = *(bv8*)&Ps[wv * 16 + lrow][lkg * 8 + ks * 32];
        bv8 bvv = *(bv8*)&Vts[n * 16 + lrow][lkg * 8 + ks * 32];
        oacc[n] = MFMA16(ap, bvv, oacc[n]);
      }
  }
  const int idx = (((s * 4 + b) * 8 + h) * 8 + qt);
  bf16* ob = o_part + (size_t)idx * 4096;
  #pragma unroll
  for (int n = 0; n < 4; ++n)
    #pragma unroll
    for (int r = 0; r < 4; ++r) {
      int row = wv * 16 + lkg * 4 + r;
      ob[row * 64 + n * 16 + lrow] = __float2bfloat16(oacc[n][r]);
    }
  if (lrow == 0) {
    #pragma unroll
    for (int r = 0; r < 4; ++r) {
      int row = wv * 16 + lkg * 4 + r;
      ml_part[idx * 128 + row] = m_run[r];
      ml_part[idx * 128 + 64 + row] = l_run[r];
    }
  }
}

// ---------------- Wouth GEMM with fused split-combine in A-staging (BK=32 body) ----------------
__global__ __launch_bounds__(256)
void wouth_gemm_kernel(const bf16* __restrict__ o_part, const float* __restrict__ ml_part,
                       const bf16* __restrict__ B, float* __restrict__ Cout) {
  __shared__ alignas(16) bf16 As[128 * 32];
  __shared__ alignas(16) bf16 Bs[128 * 32];
  const int N = 1024, K = 512;
  int row0, col0;
  xcd_remap(blockIdx.y * gridDim.x + blockIdx.x, gridDim.x, row0, col0);  // gy=16 %8==0
  const int tid = threadIdx.x;
  const int lane = tid & 63, w = tid >> 6;
  const int wr = w >> 1, wc = w & 1;
  const int lrow = lane & 15, lk = (lane >> 4) * 8;
  fv4 acc[4][4];
  #pragma unroll
  for (int m = 0; m < 4; ++m)
    #pragma unroll
    for (int n = 0; n < 4; ++n) acc[m][n] = (fv4){0.f, 0.f, 0.f, 0.f};
  const int ob0 = w * 2048;
  for (int k0 = 0; k0 < K; k0 += 32) {
    #pragma unroll
    for (int t = 0; t < 2; ++t) {
      int ob = ob0 + t * 1024;
      int ofl = ob + lane * 16;         // per-lane LDS byte offset
      int r = ofl >> 6, c8 = ((ofl >> 4) & 3) * 8;
      int grow = row0 + r, k = k0 + c8;
      int b = grow >> 9, qrow = grow & 511;
      int qt = qrow >> 6, row_in = qrow & 63;
      int h = k >> 6, d0 = k & 63;
      bv8 v[4]; float m[4], l[4];
      #pragma unroll
      for (int s = 0; s < 4; ++s) {
        int idx = (((s * 4 + b) * 8 + h) * 8 + qt);
        v[s] = *(const bv8*)&o_part[(size_t)idx * 4096 + row_in * 64 + d0];
        m[s] = ml_part[idx * 128 + row_in];
        l[s] = ml_part[idx * 128 + 64 + row_in];
      }
      float mstar = fmaxf(fmaxf(m[0], m[1]), fmaxf(m[2], m[3]));
      float ws[4]; float wsum = 0.f;
      #pragma unroll
      for (int s = 0; s < 4; ++s) { ws[s] = expf(m[s] - mstar); wsum += ws[s] * l[s]; }
      const float inv = 1.0f / wsum;
      bv8 o8;
      #pragma unroll
      for (int j = 0; j < 8; ++j) {
        float acc8 = 0.f;
        #pragma unroll
        for (int s = 0; s < 4; ++s) acc8 += ws[s] * __bfloat162float(((bf16*)&v[s])[j]);
        ((bf16*)&o8)[j] = __float2bfloat16(acc8 * inv);
      }
      *(bv8*)((char*)As + ofl) = o8;    // per-lane address
      GLOAD_LDS(B + (size_t)(col0 + r) * K + k0 + c8, (char*)Bs + ob);
    }
    __syncthreads();
    bv8 af[4], bfr[4];
    #pragma unroll
    for (int m2 = 0; m2 < 4; ++m2) af[m2] = *(bv8*)&As[(wr * 64 + m2 * 16 + lrow) * 32 + lk];
    #pragma unroll
    for (int n = 0; n < 4; ++n) bfr[n] = *(bv8*)&Bs[(wc * 64 + n * 16 + lrow) * 32 + lk];
    #pragma unroll
    for (int m2 = 0; m2 < 4; ++m2)
      #pragma unroll
      for (int n = 0; n < 4; ++n)
        acc[m2][n] = MFMA16(af[m2], bfr[n], acc[m2][n]);
    __syncthreads();
  }
  #pragma unroll
  for (int m2 = 0; m2 < 4; ++m2) {
    int gr0 = row0 + wr * 64 + m2 * 16 + (lane >> 4) * 4;
    #pragma unroll
    for (int n = 0; n < 4; ++n) {
      int gc = col0 + wc * 64 + n * 16 + lrow;
      #pragma unroll
      for (int r = 0; r < 4; ++r)
        Cout[(size_t)(gr0 + r) * N + gc] = acc[m2][n][r];
    }
  }
}

// ---------------- launcher ----------------
extern "C" void kernel_launch(void* const* d_in, const int* in_sizes, int n_in,
                              void* d_out, int out_size, void* d_ws, size_t ws_size,
                              hipStream_t stream) {
  (void)in_sizes; (void)n_in; (void)out_size; (void)ws_size;
  const float* x     = (const float*)d_in[0];
  const float* ln_w  = (const float*)d_in[1];
  const float* ln_b  = (const float*)d_in[2];
  const float* Wqkv  = (const float*)d_in[3];
  const float* Woutl = (const float*)d_in[4];
  const float* rtq   = (const float*)d_in[5];
  const float* rtkv  = (const float*)d_in[6];
  const float* gamma = (const float*)d_in[7];
  const float* Wq    = (const float*)d_in[8];
  const float* Wkv   = (const float*)d_in[9];
  const float* Wouth = (const float*)d_in[10];
  const float* nkv   = (const float*)d_in[11];
  const float* nq    = (const float*)d_in[12];
  float* out = (float*)d_out;

  char* ws = (char*)d_ws;
  size_t off = 0;
  auto alloc = [&](size_t bytes) -> void* {
    void* p = ws + off;
    off = (off + bytes + 255) & ~(size_t)255;
    return p;
  };
  bf16* ln_bf    = (bf16*)alloc(16384ull * 1024 * 2);
  bf16* qkv_bf   = (bf16*)alloc(16384ull * 1536 * 2);
  bf16* ol_bf    = (bf16*)alloc(16384ull * 512 * 2);
  bf16* Wqkv_bf  = (bf16*)alloc(1536ull * 1024 * 2);
  bf16* Woutl_bf = (bf16*)alloc(1024ull * 512 * 2);
  bf16* Wq_bf    = (bf16*)alloc(512ull * 1024 * 2);
  bf16* Wkv_bf   = (bf16*)alloc(1024ull * 1024 * 2);
  bf16* Wouth_bf = (bf16*)alloc(1024ull * 512 * 2);
  double* s_d    = (double*)alloc(32768ull * 8);
  int* iq        = (int*)alloc(2048ull * 4);
  int* ikv       = (int*)alloc(4096ull * 4);
  int* posq      = (int*)alloc(16384ull * 4);
  bf16* xq_bf    = (bf16*)alloc(2048ull * 1024 * 2);
  bf16* xkv_bf   = (bf16*)alloc(4096ull * 1024 * 2);
  bf16* qh_bf    = (bf16*)alloc(2048ull * 512 * 2);
  bf16* kvh_bf   = (bf16*)alloc(4096ull * 1024 * 2);
  float* heavy_f = (float*)alloc(2048ull * 1024 * 4);
  bf16* o_part   = (bf16*)alloc(4096ull * 4096 * 2);
  float* ml_part = (float*)alloc(4096ull * 128 * 4);

  // 1. prep: LN+sdot | weight casts | posq init
  prep_kernel<<<18448, 256, 0, stream>>>(x, ln_w, ln_b, rtq, rtkv, ln_bf, s_d,
                                         Wqkv, Woutl, Wq, Wkv, Wouth,
                                         Wqkv_bf, Woutl_bf, Wq_bf, Wkv_bf, Wouth_bf,
                                         posq);

  // 2. qkv projection GEMM (1536) + routing (8, dispatched first -> hidden)
  qkv_route_kernel<<<1544, 256, 0, stream>>>(ln_bf, Wqkv_bf, qkv_bf,
                                             s_d, iq, ikv, posq);

  // 3. local attention + heavy-path gather (merged)
  la_gather_kernel<<<8192, 256, 0, stream>>>(qkv_bf, ol_bf, x, gamma, iq, ikv, xq_bf, xkv_bf);

  // 4. heavy projections (merged Wkv + Wq)
  wqkv_kernel<<<320, 256, 0, stream>>>(xkv_bf, Wkv_bf, kvh_bf, xq_bf, Wq_bf, qh_bf);

  // 5. heavy attention split-K partials
  heavy_attn_split_kernel<<<dim3(8, 8, 16), 256, 0, stream>>>(qh_bf, kvh_bf, nkv, o_part, ml_part);

  // 6. Wouth GEMM with fused combine
  wouth_gemm_kernel<<<dim3(8, 16), 256, 0, stream>>>(o_part, ml_part, Wouth_bf, heavy_f);

  // 7. light output GEMM + fused combine (heavy scatter / null_q) -> d_out
  gemm_bt<2><<<dim3(8, 128), 256, 0, stream>>>(ol_bf, Woutl_bf, out, 1024, 512,
                                               posq, heavy_f, nq);
}